// Round 6
// baseline (298.190 us; speedup 1.0000x reference)
//
#include <hip/hip_runtime.h>
#include <stdint.h>

typedef __attribute__((ext_vector_type(8))) short short8;
typedef __attribute__((ext_vector_type(4))) float float4v;

#define HW   4096
#define CC   256
#define SEQQ 32
#define BSZ  32
#define RPB  128   // rows per block (4 waves x 32 rows) -- r4 best config

// Tiled ctx layout (per batch): [s>>2][c>>4][s&3][c&15] shorts.
// s-group = 16 c-tiles x 64 = 1024 shorts, padded to 1032 (bank de-phase).
#define SGRP     1032
#define CTXT_SZ  (8 * SGRP)          // 8256 shorts per batch

static __device__ __forceinline__ uint16_t f2bf(float f) {
  union { float f; uint32_t u; } v; v.f = f;
  uint32_t r = v.u + 0x7FFFu + ((v.u >> 16) & 1u);
  return (uint16_t)(r >> 16);
}
static __device__ __forceinline__ float bf2f(uint16_t h) {
  union { uint32_t u; float f; } v; v.u = ((uint32_t)h) << 16;
  return v.f;
}

// ---------------------------------------------------------------------------
// Prep: ctx = context @ W (fp32 accum), split to bf16 hi/lo in TILED layout,
// plus mask -> 32-word bitmask (with storage-format autodetection).
// ---------------------------------------------------------------------------
extern "C" __global__ __launch_bounds__(256) void prep_kernel(
    const float* __restrict__ ctx_in,   // [32][32][256]
    const float* __restrict__ Wp,       // [256][256]
    const void*  __restrict__ mask,     // [32][32] unknown storage
    uint32_t* __restrict__ maskbits_ws, // [32] bitmask words
    uint16_t* __restrict__ hiT_ws,      // [32][8256] tiled bf16 hi
    uint16_t* __restrict__ loT_ws)      // [32][8256] tiled bf16 lo
{
  const int t = threadIdx.x;
  if (blockIdx.x == 256) {
    __shared__ int byteFlag;
    if (t == 0) byteFlag = 0;
    __syncthreads();
    const uint8_t* mb = (const uint8_t*)mask;
    int nz = 0;
    for (int i = t; i < 1024; i += 256)
      if ((i & 3) == 1 && mb[i] != 0) nz = 1;
    if (nz) atomicOr(&byteFlag, 1);
    __syncthreads();
    const bool byteMode = (byteFlag != 0);
    const uint32_t* mw32 = (const uint32_t*)mask;
    if (t < 32) {
      uint32_t bits = 0;
      for (int s = 0; s < 32; ++s) {
        bool m = byteMode ? (mb[t * 32 + s] != 0) : (mw32[t * 32 + s] != 0);
        if (m) bits |= (1u << s);
      }
      maskbits_ws[t] = bits;
    }
    return;
  }

  const int r0 = blockIdx.x * 4;
  __shared__ float crow[4][CC];
  for (int i = t; i < 1024; i += 256)
    crow[i >> 8][i & 255] = ctx_in[(size_t)r0 * CC + i];
  __syncthreads();

  const int j  = t >> 6;
  const int c4 = (t & 63) << 2;
  float4v acc = {0.f, 0.f, 0.f, 0.f};
  #pragma unroll 8
  for (int d = 0; d < CC; ++d) {
    float s = crow[j][d];
    const float4 wv = *(const float4*)&Wp[(size_t)d * CC + c4];
    acc[0] += s * wv.x; acc[1] += s * wv.y;
    acc[2] += s * wv.z; acc[3] += s * wv.w;
  }

  const int row = r0 + j, bb = row >> 5, ss = row & 31;
  const size_t base = (size_t)bb * CTXT_SZ + (ss >> 2) * SGRP + (ss & 3) * 16;
  #pragma unroll
  for (int q = 0; q < 4; ++q) {
    const int c = c4 + q;
    const float v = acc[q];
    const uint16_t h  = f2bf(v);
    const uint16_t lo = f2bf(v - bf2f(h));
    const size_t idx = base + (c >> 4) * 64 + (c & 15);
    hiT_ws[idx] = h;
    loT_ws[idx] = lo;
  }
}

// One 16-row tile. Phase1: split-bf16 MFMA (swapped operands), lane-owns-row
// softmax. r6 change: the pa fragment is redistributed IN-REGISTER via 8
// __shfl + 4 selects (replacing the pL LDS round-trip; bit-identical packed
// bf16 words) -- frees 5 KB LDS so 3 blocks/CU fit. out1/out0 keep the
// XOR-swizzled LDS transpose -> full-128B-line global stores (r4 win).
#define COMPUTE_TILE(XA, XB, TBASE)                                           \
  {                                                                           \
    float4v acc0 = {0.f, 0.f, 0.f, 0.f};                                      \
    float4v acc1 = {0.f, 0.f, 0.f, 0.f};                                      \
    _Pragma("unroll")                                                         \
    for (int k0 = 0; k0 < 8; ++k0) {                                          \
      float xv[8] = {XA[k0].x, XA[k0].y, XA[k0].z, XA[k0].w,                  \
                     XB[k0].x, XB[k0].y, XB[k0].z, XB[k0].w};                 \
      short8 ah, al;                                                          \
      _Pragma("unroll")                                                       \
      for (int jj = 0; jj < 8; ++jj) {                                        \
        uint32_t u = __float_as_uint(xv[jj]);                                 \
        ah[jj] = (short)(u >> 16);                                            \
        float rr_ = xv[jj] - __uint_as_float(u & 0xFFFF0000u);                \
        al[jj] = (short)(__float_as_uint(rr_) >> 16);                         \
      }                                                                       \
      const int ka = sbase + k0 * 128;                                        \
      short8 bh0 = *(const short8*)&hiT[ka];                                  \
      short8 bl0 = *(const short8*)&loT[ka];                                  \
      short8 bh1 = *(const short8*)&hiT[ka + 4 * SGRP];                       \
      short8 bl1 = *(const short8*)&loT[ka + 4 * SGRP];                       \
      acc0 = __builtin_amdgcn_mfma_f32_16x16x32_bf16(bh0, ah, acc0, 0, 0, 0); \
      acc0 = __builtin_amdgcn_mfma_f32_16x16x32_bf16(bl0, ah, acc0, 0, 0, 0); \
      acc0 = __builtin_amdgcn_mfma_f32_16x16x32_bf16(bh0, al, acc0, 0, 0, 0); \
      acc1 = __builtin_amdgcn_mfma_f32_16x16x32_bf16(bh1, ah, acc1, 0, 0, 0); \
      acc1 = __builtin_amdgcn_mfma_f32_16x16x32_bf16(bl1, ah, acc1, 0, 0, 0); \
      acc1 = __builtin_amdgcn_mfma_f32_16x16x32_bf16(bh1, al, acc1, 0, 0, 0); \
    }                                                                         \
    const int n = (TBASE) + l15;                                              \
    const uint32_t mwd = maskW[n & 31];                                       \
    float v[8];                                                               \
    _Pragma("unroll")                                                         \
    for (int r = 0; r < 4; ++r) {                                             \
      v[r]     = (mwd & (1u << (quad * 4 + r)))      ? -1e30f : acc0[r];      \
      v[4 + r] = (mwd & (1u << (16 + quad * 4 + r))) ? -1e30f : acc1[r];      \
    }                                                                         \
    float mx = v[0];                                                          \
    _Pragma("unroll")                                                         \
    for (int jq = 1; jq < 8; ++jq) mx = fmaxf(mx, v[jq]);                     \
    mx = fmaxf(mx, __shfl_xor(mx, 16, 64));                                   \
    mx = fmaxf(mx, __shfl_xor(mx, 32, 64));                                   \
    float e[8], sm = 0.f;                                                     \
    _Pragma("unroll")                                                         \
    for (int jq = 0; jq < 8; ++jq) { e[jq] = __expf(v[jq] - mx); sm += e[jq]; } \
    sm += __shfl_xor(sm, 16, 64);                                             \
    sm += __shfl_xor(sm, 32, 64);                                             \
    const float inv = 1.0f / sm;                                              \
    float p[8];                                                               \
    _Pragma("unroll")                                                         \
    for (int jq = 0; jq < 8; ++jq) p[jq] = e[jq] * inv;                       \
    /* out1 via XOR-swizzled LDS transpose ([16][32] f32, 8 slots/row) */     \
    const int r8 = l15 & 7;                                                   \
    *(float4*)&ostW[l15 * 32 + ((quad ^ r8) << 2)] =                          \
        make_float4(p[0], p[1], p[2], p[3]);                                  \
    *(float4*)&ostW[l15 * 32 + (((4 + quad) ^ r8) << 2)] =                    \
        make_float4(p[4], p[5], p[6], p[7]);                                  \
    uint32_t w0 = (uint32_t)f2bf(p[0]) | ((uint32_t)f2bf(p[1]) << 16);        \
    uint32_t w1 = (uint32_t)f2bf(p[2]) | ((uint32_t)f2bf(p[3]) << 16);        \
    uint32_t w2 = (uint32_t)f2bf(p[4]) | ((uint32_t)f2bf(p[5]) << 16);        \
    uint32_t w3 = (uint32_t)f2bf(p[6]) | ((uint32_t)f2bf(p[7]) << 16);        \
    _Pragma("unroll")                                                         \
    for (int i2 = 0; i2 < 2; ++i2) {                                          \
      const int rr = 8 * i2 + (lane >> 3);                                    \
      const int mm = lane & 7;                                                \
      float4 vv = *(const float4*)&ostW[rr * 32 + ((mm ^ (rr & 7)) << 2)];    \
      *(float4*)(out1 + ((size_t)b * HW + (TBASE) + rr) * SEQQ + mm * 4) = vv;\
    }                                                                         \
    /* pa fragment: in-register redistribution (replaces pL LDS round-trip). \
       lane (q,l15) needs packed P-words of owner lanes q'=(2q&3),(2q&3)+1:  \
       their w0/w1 (s<16, consumers q<2) or w2/w3 (s>=16, consumers q>=2). */ \
    const int src0 = (((quad * 2) & 3) << 4) + l15;                           \
    const int src1 = src0 + 16;                                               \
    int A0 = __shfl((int)w0, src0, 64), A1 = __shfl((int)w1, src0, 64);       \
    int A2 = __shfl((int)w0, src1, 64), A3 = __shfl((int)w1, src1, 64);       \
    int B0 = __shfl((int)w2, src0, 64), B1 = __shfl((int)w3, src0, 64);       \
    int B2 = __shfl((int)w2, src1, 64), B3 = __shfl((int)w3, src1, 64);       \
    union { uint32_t u[4]; short8 s; } pau;                                   \
    pau.u[0] = (uint32_t)((quad < 2) ? A0 : B0);                              \
    pau.u[1] = (uint32_t)((quad < 2) ? A1 : B1);                              \
    pau.u[2] = (uint32_t)((quad < 2) ? A2 : B2);                              \
    pau.u[3] = (uint32_t)((quad < 2) ? A3 : B3);                              \
    short8 pa = pau.s;                                                        \
    /* phase 2: per 64-ch group, MFMA -> LDS transpose -> full-line stores */ \
    _Pragma("unroll")                                                         \
    for (int cg = 0; cg < 4; ++cg) {                                          \
      _Pragma("unroll")                                                       \
      for (int j2 = 0; j2 < 4; ++j2) {                                        \
        const int ct = cg * 4 + j2;                                           \
        short8 bfr;                                                           \
        _Pragma("unroll")                                                     \
        for (int jj = 0; jj < 8; ++jj)                                        \
          bfr[jj] = (short)hiT[cbase + (jj >> 2) * SGRP + ct * 64 + (jj & 3) * 16]; \
        float4v z = {0.f, 0.f, 0.f, 0.f};                                     \
        float4v dd = __builtin_amdgcn_mfma_f32_16x16x32_bf16(bfr, pa, z, 0, 0, 0); \
        const int ss = j2 * 4 + quad;                                         \
        *(float4v*)&ostW[l15 * 64 + ((ss ^ l15) << 2)] = dd;                  \
      }                                                                       \
      _Pragma("unroll")                                                       \
      for (int i2 = 0; i2 < 4; ++i2) {                                        \
        const int rr = 4 * i2 + (lane >> 4);                                  \
        const int mm = lane & 15;                                             \
        float4 vv = *(const float4*)&ostW[rr * 64 + ((mm ^ rr) << 2)];        \
        *(float4*)(out0 + ((size_t)b * HW + (TBASE) + rr) * CC + cg * 64 + mm * 4) = vv; \
      }                                                                       \
    }                                                                         \
  }

// ---------------------------------------------------------------------------
// Main fused kernel. r6 = r4 (best known: 1024 blocks, 2 chunks/wave, plain
// full-line stores) + pL->shuffle (LDS 54.8 -> 48.4 KB => 3 blocks/CU for
// +50% cross-block phase stagger).
// ---------------------------------------------------------------------------
extern "C" __global__ __launch_bounds__(256, 3) void attn_main(
    const float* __restrict__ x,        // [32][4096][256]
    const uint8_t* __restrict__ ws,
    float* __restrict__ out0,           // weighted_context [32][4096][256]
    float* __restrict__ out1)           // word_attn        [32][4096][32]
{
  const uint32_t* maskbits_ws = (const uint32_t*)ws;
  const uint16_t* hiT_ws = (const uint16_t*)(ws + 128);
  const uint16_t* loT_ws = hiT_ws + (size_t)BSZ * CTXT_SZ;

  __shared__ __align__(16) uint16_t hiT[CTXT_SZ];      // 16512 B
  __shared__ __align__(16) uint16_t loT[CTXT_SZ];      // 16512 B
  __shared__ __align__(16) float    oStgF[4 * 1024];   // 16384 B (4KB/wave)
  __shared__ uint32_t maskW[32];                       // total ~48.4 KB

  const int tid = threadIdx.x;
  const int b   = blockIdx.y;
  const int n0  = blockIdx.x * RPB;

  const int w    = tid >> 6;
  const int lane = tid & 63;
  const int l15  = lane & 15;
  const int quad = lane >> 4;
  const int nwave = n0 + w * 32;
  float* ostW = &oStgF[w * 1024];

  const uint4* sHi = (const uint4*)(hiT_ws + (size_t)b * CTXT_SZ);
  const uint4* sLo = (const uint4*)(loT_ws + (size_t)b * CTXT_SZ);

  // ---- issue staging loads (regs) ----
  uint4 hS[4], lS[4];
  #pragma unroll
  for (int k = 0; k < 4; ++k) {
    hS[k] = sHi[tid + k * 256];
    lS[k] = sLo[tid + k * 256];
  }

  // ---- issue ALL tile-0 x loads (16 dwordx4 in flight) ----
  const float* xrow0 = x + ((size_t)b * HW + nwave + l15) * CC + quad * 8;
  float4 xa0[8], xb0[8];
  #pragma unroll
  for (int k0 = 0; k0 < 8; ++k0) {
    xa0[k0] = *(const float4*)(xrow0 + k0 * 32);
    xb0[k0] = *(const float4*)(xrow0 + k0 * 32 + 4);
  }
  asm volatile("" ::: "memory");   // pin: loads above may not sink below

  // ---- LDS writes + barrier ----
  {
    uint4* dHi = (uint4*)hiT;
    uint4* dLo = (uint4*)loT;
    #pragma unroll
    for (int k = 0; k < 4; ++k) {
      dHi[tid + k * 256] = hS[k];
      dLo[tid + k * 256] = lS[k];
    }
    if (tid < 8) { dHi[1024 + tid] = sHi[1024 + tid]; dLo[1024 + tid] = sLo[1024 + tid]; }
    if (tid < 32) maskW[tid] = maskbits_ws[tid];
  }
  __syncthreads();

  // ---- issue ALL tile-1 x loads; latency hides under tile-0 compute ----
  const float* xrow1 = xrow0 + 16 * CC;
  float4 xa1[8], xb1[8];
  #pragma unroll
  for (int k0 = 0; k0 < 8; ++k0) {
    xa1[k0] = *(const float4*)(xrow1 + k0 * 32);
    xb1[k0] = *(const float4*)(xrow1 + k0 * 32 + 4);
  }
  asm volatile("" ::: "memory");   // pin: tile-1 loads issue before t0 compute

  const int sbase = (l15 >> 2) * SGRP + (l15 & 3) * 16 + (quad >> 1) * 64 + (quad & 1) * 8;
  const int cbase = quad * 2 * SGRP + l15;

  COMPUTE_TILE(xa0, xb0, nwave);
  COMPUTE_TILE(xa1, xb1, nwave + 16);
}

// ---------------------------------------------------------------------------
extern "C" void kernel_launch(void* const* d_in, const int* in_sizes, int n_in,
                              void* d_out, int out_size, void* d_ws, size_t ws_size,
                              hipStream_t stream) {
  const float* x      = (const float*)d_in[0];
  // d_in[1] = sentence (unused by reference call())
  const float* ctx_in = (const float*)d_in[2];
  const void*  mask   = d_in[3];
  const float* Wp     = (const float*)d_in[4];

  float* out0 = (float*)d_out;                       // [32][4096][256]
  float* out1 = out0 + (size_t)BSZ * HW * CC;        // [32][4096][32]

  uint8_t*  ws          = (uint8_t*)d_ws;
  uint32_t* maskbits_ws = (uint32_t*)ws;                         // 128 B
  uint16_t* hiT_ws      = (uint16_t*)(ws + 128);                 // 528384 B
  uint16_t* loT_ws      = hiT_ws + (size_t)BSZ * CTXT_SZ;        // 528384 B

  prep_kernel<<<257, 256, 0, stream>>>(ctx_in, Wp, mask, maskbits_ws,
                                       hiT_ws, loT_ws);
  attn_main<<<dim3(HW / RPB, BSZ), 256, 0, stream>>>(x, ws, out0, out1);
}

// Round 7
// 281.292 us; speedup vs baseline: 1.0601x; 1.0601x over previous
//
#include <hip/hip_runtime.h>
#include <stdint.h>

typedef __attribute__((ext_vector_type(8))) short short8;
typedef __attribute__((ext_vector_type(4))) float float4v;

#define HW   4096
#define CC   256
#define SEQQ 32
#define BSZ  32
#define RPB  128   // rows per block (4 waves x 32 rows) -- r4 best config

// Tiled ctx layout (per batch): [s>>2][c>>4][s&3][c&15] shorts.
// s-group = 16 c-tiles x 64 = 1024 shorts, padded to 1032 (bank de-phase).
#define SGRP     1032
#define CTXT_SZ  (8 * SGRP)          // 8256 shorts per batch
#define PSTR_P   40                  // pL row stride (shorts)

static __device__ __forceinline__ uint16_t f2bf(float f) {
  union { float f; uint32_t u; } v; v.f = f;
  uint32_t r = v.u + 0x7FFFu + ((v.u >> 16) & 1u);
  return (uint16_t)(r >> 16);
}
static __device__ __forceinline__ float bf2f(uint16_t h) {
  union { uint32_t u; float f; } v; v.u = ((uint32_t)h) << 16;
  return v.f;
}

// ---------------------------------------------------------------------------
// Prep: ctx = context @ W (fp32 accum), split to bf16 hi/lo in TILED layout,
// plus mask -> 32-word bitmask (with storage-format autodetection).
// ---------------------------------------------------------------------------
extern "C" __global__ __launch_bounds__(256) void prep_kernel(
    const float* __restrict__ ctx_in,   // [32][32][256]
    const float* __restrict__ Wp,       // [256][256]
    const void*  __restrict__ mask,     // [32][32] unknown storage
    uint32_t* __restrict__ maskbits_ws, // [32] bitmask words
    uint16_t* __restrict__ hiT_ws,      // [32][8256] tiled bf16 hi
    uint16_t* __restrict__ loT_ws)      // [32][8256] tiled bf16 lo
{
  const int t = threadIdx.x;
  if (blockIdx.x == 256) {
    __shared__ int byteFlag;
    if (t == 0) byteFlag = 0;
    __syncthreads();
    const uint8_t* mb = (const uint8_t*)mask;
    int nz = 0;
    for (int i = t; i < 1024; i += 256)
      if ((i & 3) == 1 && mb[i] != 0) nz = 1;
    if (nz) atomicOr(&byteFlag, 1);
    __syncthreads();
    const bool byteMode = (byteFlag != 0);
    const uint32_t* mw32 = (const uint32_t*)mask;
    if (t < 32) {
      uint32_t bits = 0;
      for (int s = 0; s < 32; ++s) {
        bool m = byteMode ? (mb[t * 32 + s] != 0) : (mw32[t * 32 + s] != 0);
        if (m) bits |= (1u << s);
      }
      maskbits_ws[t] = bits;
    }
    return;
  }

  const int r0 = blockIdx.x * 4;
  __shared__ float crow[4][CC];
  for (int i = t; i < 1024; i += 256)
    crow[i >> 8][i & 255] = ctx_in[(size_t)r0 * CC + i];
  __syncthreads();

  const int j  = t >> 6;
  const int c4 = (t & 63) << 2;
  float4v acc = {0.f, 0.f, 0.f, 0.f};
  #pragma unroll 8
  for (int d = 0; d < CC; ++d) {
    float s = crow[j][d];
    const float4 wv = *(const float4*)&Wp[(size_t)d * CC + c4];
    acc[0] += s * wv.x; acc[1] += s * wv.y;
    acc[2] += s * wv.z; acc[3] += s * wv.w;
  }

  const int row = r0 + j, bb = row >> 5, ss = row & 31;
  const size_t base = (size_t)bb * CTXT_SZ + (ss >> 2) * SGRP + (ss & 3) * 16;
  #pragma unroll
  for (int q = 0; q < 4; ++q) {
    const int c = c4 + q;
    const float v = acc[q];
    const uint16_t h  = f2bf(v);
    const uint16_t lo = f2bf(v - bf2f(h));
    const size_t idx = base + (c >> 4) * 64 + (c & 15);
    hiT_ws[idx] = h;
    loT_ws[idx] = lo;
  }
}

// One 16-row tile -- byte-identical to round-4 (best known) EXCEPT the two
// global output stores are NON-TEMPORAL. Outputs are written once and never
// re-read in-kernel; NT keeps them from evicting x from L3 (134 MB of x vs
// 256 MB L3; r4 showed ~half of x falling out to HBM, r6 showed the traffic
// is cache-pressure-sensitive). Store shape (full 128B lines) unchanged.
#define COMPUTE_TILE(XA, XB, TBASE)                                           \
  {                                                                           \
    float4v acc0 = {0.f, 0.f, 0.f, 0.f};                                      \
    float4v acc1 = {0.f, 0.f, 0.f, 0.f};                                      \
    _Pragma("unroll")                                                         \
    for (int k0 = 0; k0 < 8; ++k0) {                                          \
      float xv[8] = {XA[k0].x, XA[k0].y, XA[k0].z, XA[k0].w,                  \
                     XB[k0].x, XB[k0].y, XB[k0].z, XB[k0].w};                 \
      short8 ah, al;                                                          \
      _Pragma("unroll")                                                       \
      for (int jj = 0; jj < 8; ++jj) {                                        \
        uint32_t u = __float_as_uint(xv[jj]);                                 \
        ah[jj] = (short)(u >> 16);                                            \
        float rr_ = xv[jj] - __uint_as_float(u & 0xFFFF0000u);                \
        al[jj] = (short)(__float_as_uint(rr_) >> 16);                         \
      }                                                                       \
      const int ka = sbase + k0 * 128;                                        \
      short8 bh0 = *(const short8*)&hiT[ka];                                  \
      short8 bl0 = *(const short8*)&loT[ka];                                  \
      short8 bh1 = *(const short8*)&hiT[ka + 4 * SGRP];                       \
      short8 bl1 = *(const short8*)&loT[ka + 4 * SGRP];                       \
      acc0 = __builtin_amdgcn_mfma_f32_16x16x32_bf16(bh0, ah, acc0, 0, 0, 0); \
      acc0 = __builtin_amdgcn_mfma_f32_16x16x32_bf16(bl0, ah, acc0, 0, 0, 0); \
      acc0 = __builtin_amdgcn_mfma_f32_16x16x32_bf16(bh0, al, acc0, 0, 0, 0); \
      acc1 = __builtin_amdgcn_mfma_f32_16x16x32_bf16(bh1, ah, acc1, 0, 0, 0); \
      acc1 = __builtin_amdgcn_mfma_f32_16x16x32_bf16(bl1, ah, acc1, 0, 0, 0); \
      acc1 = __builtin_amdgcn_mfma_f32_16x16x32_bf16(bh1, al, acc1, 0, 0, 0); \
    }                                                                         \
    const int n = (TBASE) + l15;                                              \
    const uint32_t mwd = maskW[n & 31];                                       \
    float v[8];                                                               \
    _Pragma("unroll")                                                         \
    for (int r = 0; r < 4; ++r) {                                             \
      v[r]     = (mwd & (1u << (quad * 4 + r)))      ? -1e30f : acc0[r];      \
      v[4 + r] = (mwd & (1u << (16 + quad * 4 + r))) ? -1e30f : acc1[r];      \
    }                                                                         \
    float mx = v[0];                                                          \
    _Pragma("unroll")                                                         \
    for (int jq = 1; jq < 8; ++jq) mx = fmaxf(mx, v[jq]);                     \
    mx = fmaxf(mx, __shfl_xor(mx, 16, 64));                                   \
    mx = fmaxf(mx, __shfl_xor(mx, 32, 64));                                   \
    float e[8], sm = 0.f;                                                     \
    _Pragma("unroll")                                                         \
    for (int jq = 0; jq < 8; ++jq) { e[jq] = __expf(v[jq] - mx); sm += e[jq]; } \
    sm += __shfl_xor(sm, 16, 64);                                             \
    sm += __shfl_xor(sm, 32, 64);                                             \
    const float inv = 1.0f / sm;                                              \
    float p[8];                                                               \
    _Pragma("unroll")                                                         \
    for (int jq = 0; jq < 8; ++jq) p[jq] = e[jq] * inv;                       \
    /* out1 via XOR-swizzled LDS transpose ([16][32] f32, 8 slots/row) */     \
    const int r8 = l15 & 7;                                                   \
    *(float4*)&ostW[l15 * 32 + ((quad ^ r8) << 2)] =                          \
        make_float4(p[0], p[1], p[2], p[3]);                                  \
    *(float4*)&ostW[l15 * 32 + (((4 + quad) ^ r8) << 2)] =                    \
        make_float4(p[4], p[5], p[6], p[7]);                                  \
    uint32_t w0 = (uint32_t)f2bf(p[0]) | ((uint32_t)f2bf(p[1]) << 16);        \
    uint32_t w1 = (uint32_t)f2bf(p[2]) | ((uint32_t)f2bf(p[3]) << 16);        \
    uint32_t w2 = (uint32_t)f2bf(p[4]) | ((uint32_t)f2bf(p[5]) << 16);        \
    uint32_t w3 = (uint32_t)f2bf(p[6]) | ((uint32_t)f2bf(p[7]) << 16);        \
    uint16_t* prow = &pL[(w * 16 + l15) * PSTR_P];                            \
    *(uint2*)(prow + quad * 4)      = make_uint2(w0, w1);                     \
    *(uint2*)(prow + 16 + quad * 4) = make_uint2(w2, w3);                     \
    _Pragma("unroll")                                                         \
    for (int i2 = 0; i2 < 2; ++i2) {                                          \
      const int rr = 8 * i2 + (lane >> 3);                                    \
      const int mm = lane & 7;                                                \
      float4v vv = *(const float4v*)&ostW[rr * 32 + ((mm ^ (rr & 7)) << 2)];  \
      __builtin_nontemporal_store(vv,                                         \
        (float4v*)(out1 + ((size_t)b * HW + (TBASE) + rr) * SEQQ + mm * 4));  \
    }                                                                         \
    /* phase 2: per 64-ch group, MFMA -> LDS transpose -> full-line stores */ \
    short8 pa = *(const short8*)&pL[(w * 16 + l15) * PSTR_P + quad * 8];      \
    _Pragma("unroll")                                                         \
    for (int cg = 0; cg < 4; ++cg) {                                          \
      _Pragma("unroll")                                                       \
      for (int j2 = 0; j2 < 4; ++j2) {                                        \
        const int ct = cg * 4 + j2;                                           \
        short8 bfr;                                                           \
        _Pragma("unroll")                                                     \
        for (int jj = 0; jj < 8; ++jj)                                        \
          bfr[jj] = (short)hiT[cbase + (jj >> 2) * SGRP + ct * 64 + (jj & 3) * 16]; \
        float4v z = {0.f, 0.f, 0.f, 0.f};                                     \
        float4v dd = __builtin_amdgcn_mfma_f32_16x16x32_bf16(bfr, pa, z, 0, 0, 0); \
        const int ss = j2 * 4 + quad;                                         \
        *(float4v*)&ostW[l15 * 64 + ((ss ^ l15) << 2)] = dd;                  \
      }                                                                       \
      _Pragma("unroll")                                                       \
      for (int i2 = 0; i2 < 4; ++i2) {                                        \
        const int rr = 4 * i2 + (lane >> 4);                                  \
        const int mm = lane & 15;                                             \
        float4v vv = *(const float4v*)&ostW[rr * 64 + ((mm ^ rr) << 2)];      \
        __builtin_nontemporal_store(vv,                                       \
          (float4v*)(out0 + ((size_t)b * HW + (TBASE) + rr) * CC + cg * 64 + mm * 4)); \
      }                                                                       \
    }                                                                         \
  }

// ---------------------------------------------------------------------------
// Main fused kernel. r7 = EXACT r4 structure (best known: 1024 blocks,
// 2 blocks/CU, 2 chunks/wave, pL round-trip, full-line store epilogues)
// with ONE isolated change: non-temporal output stores.
// ---------------------------------------------------------------------------
extern "C" __global__ __launch_bounds__(256, 2) void attn_main(
    const float* __restrict__ x,        // [32][4096][256]
    const uint8_t* __restrict__ ws,
    float* __restrict__ out0,           // weighted_context [32][4096][256]
    float* __restrict__ out1)           // word_attn        [32][4096][32]
{
  const uint32_t* maskbits_ws = (const uint32_t*)ws;
  const uint16_t* hiT_ws = (const uint16_t*)(ws + 128);
  const uint16_t* loT_ws = hiT_ws + (size_t)BSZ * CTXT_SZ;

  __shared__ __align__(16) uint16_t hiT[CTXT_SZ];      // 16512 B
  __shared__ __align__(16) uint16_t loT[CTXT_SZ];      // 16512 B
  __shared__ __align__(16) uint16_t pL[64 * PSTR_P];   // 5120 B
  __shared__ __align__(16) float    oStgF[4 * 1024];   // 16384 B (4KB/wave)
  __shared__ uint32_t maskW[32];

  const int tid = threadIdx.x;
  const int b   = blockIdx.y;
  const int n0  = blockIdx.x * RPB;

  const int w    = tid >> 6;
  const int lane = tid & 63;
  const int l15  = lane & 15;
  const int quad = lane >> 4;
  const int nwave = n0 + w * 32;
  float* ostW = &oStgF[w * 1024];

  const uint4* sHi = (const uint4*)(hiT_ws + (size_t)b * CTXT_SZ);
  const uint4* sLo = (const uint4*)(loT_ws + (size_t)b * CTXT_SZ);

  // ---- issue staging loads (regs) ----
  uint4 hS[4], lS[4];
  #pragma unroll
  for (int k = 0; k < 4; ++k) {
    hS[k] = sHi[tid + k * 256];
    lS[k] = sLo[tid + k * 256];
  }

  // ---- issue ALL tile-0 x loads (16 dwordx4 in flight) ----
  const float* xrow0 = x + ((size_t)b * HW + nwave + l15) * CC + quad * 8;
  float4 xa0[8], xb0[8];
  #pragma unroll
  for (int k0 = 0; k0 < 8; ++k0) {
    xa0[k0] = *(const float4*)(xrow0 + k0 * 32);
    xb0[k0] = *(const float4*)(xrow0 + k0 * 32 + 4);
  }
  asm volatile("" ::: "memory");   // pin: loads above may not sink below

  // ---- LDS writes + barrier ----
  {
    uint4* dHi = (uint4*)hiT;
    uint4* dLo = (uint4*)loT;
    #pragma unroll
    for (int k = 0; k < 4; ++k) {
      dHi[tid + k * 256] = hS[k];
      dLo[tid + k * 256] = lS[k];
    }
    if (tid < 8) { dHi[1024 + tid] = sHi[1024 + tid]; dLo[1024 + tid] = sLo[1024 + tid]; }
    if (tid < 32) maskW[tid] = maskbits_ws[tid];
  }
  __syncthreads();

  // ---- issue ALL tile-1 x loads; latency hides under tile-0 compute ----
  const float* xrow1 = xrow0 + 16 * CC;
  float4 xa1[8], xb1[8];
  #pragma unroll
  for (int k0 = 0; k0 < 8; ++k0) {
    xa1[k0] = *(const float4*)(xrow1 + k0 * 32);
    xb1[k0] = *(const float4*)(xrow1 + k0 * 32 + 4);
  }
  asm volatile("" ::: "memory");   // pin: tile-1 loads issue before t0 compute

  const int sbase = (l15 >> 2) * SGRP + (l15 & 3) * 16 + (quad >> 1) * 64 + (quad & 1) * 8;
  const int cbase = quad * 2 * SGRP + l15;

  COMPUTE_TILE(xa0, xb0, nwave);
  COMPUTE_TILE(xa1, xb1, nwave + 16);
}

// ---------------------------------------------------------------------------
extern "C" void kernel_launch(void* const* d_in, const int* in_sizes, int n_in,
                              void* d_out, int out_size, void* d_ws, size_t ws_size,
                              hipStream_t stream) {
  const float* x      = (const float*)d_in[0];
  // d_in[1] = sentence (unused by reference call())
  const float* ctx_in = (const float*)d_in[2];
  const void*  mask   = d_in[3];
  const float* Wp     = (const float*)d_in[4];

  float* out0 = (float*)d_out;                       // [32][4096][256]
  float* out1 = out0 + (size_t)BSZ * HW * CC;        // [32][4096][32]

  uint8_t*  ws          = (uint8_t*)d_ws;
  uint32_t* maskbits_ws = (uint32_t*)ws;                         // 128 B
  uint16_t* hiT_ws      = (uint16_t*)(ws + 128);                 // 528384 B
  uint16_t* loT_ws      = hiT_ws + (size_t)BSZ * CTXT_SZ;        // 528384 B

  prep_kernel<<<257, 256, 0, stream>>>(ctx_in, Wp, mask, maskbits_ws,
                                       hiT_ws, loT_ws);
  attn_main<<<dim3(HW / RPB, BSZ), 256, 0, stream>>>(x, ws, out0, out1);
}